// Round 1
// baseline (881.659 us; speedup 1.0000x reference)
//
#include <hip/hip_runtime.h>
#include <hip/hip_bf16.h>
#include <stdint.h>

#define NCLOTHES 50000
#define CPAD     50048   // 391 * 128
#define FDIM     256
#define NBATCH   1024
#define SCALEF   16.0f
#define EPSW     0.1f
#define MAXPOS   1024

typedef __attribute__((ext_vector_type(8))) short short8;
typedef __attribute__((ext_vector_type(4))) float f32x4;

__device__ __forceinline__ void gload_lds16(const void* gsrc, void* ldst) {
    __builtin_amdgcn_global_load_lds(
        (const __attribute__((address_space(1))) void*)gsrc,
        (__attribute__((address_space(3))) void*)ldst, 16, 0, 0);
}

__global__ void zero_kernel(float* negsum, int* poscount) {
    int i = blockIdx.x * blockDim.x + threadIdx.x;
    if (i < NBATCH) { negsum[i] = 0.f; poscount[i] = 0; }
}

// inputs_norm * SCALE -> bf16 A [1024][256]; one block (256 thr) per row
__global__ void anorm_kernel(const float* __restrict__ in, __hip_bfloat16* __restrict__ A) {
    int b = blockIdx.x, t = threadIdx.x;
    float x = in[b * FDIM + t];
    float ss = x * x;
    #pragma unroll
    for (int o = 32; o > 0; o >>= 1) ss += __shfl_xor(ss, o);
    __shared__ float sh[4];
    if ((t & 63) == 0) sh[t >> 6] = ss;
    __syncthreads();
    float tot = sh[0] + sh[1] + sh[2] + sh[3];
    float r = SCALEF / fmaxf(sqrtf(tot), 1e-12f);
    A[b * FDIM + t] = __float2bfloat16(x * r);
}

// scatter-mean (gather form) + l2-normalize -> bf16 B [CPAD][256]; block per clothes id
__global__ void bnorm_kernel(const float* __restrict__ fm, const float* __restrict__ in,
                             const int* __restrict__ tg, __hip_bfloat16* __restrict__ Bm) {
    int c = blockIdx.x, t = threadIdx.x;
    if (c >= NCLOTHES) { Bm[(size_t)c * FDIM + t] = __float2bfloat16(0.f); return; }
    __shared__ int mlist[32];
    __shared__ int mcount;
    if (t == 0) mcount = 0;
    __syncthreads();
    #pragma unroll
    for (int j = 0; j < 4; ++j) {
        int b = t + j * 256;
        if (tg[b] == c) { int p = atomicAdd(&mcount, 1); if (p < 32) mlist[p] = b; }
    }
    __syncthreads();
    int n = mcount;
    float v;
    if (n == 0) {
        v = fm[(size_t)c * FDIM + t];
    } else {
        v = 0.f;
        for (int i = 0; i < n; ++i) v += in[mlist[i] * FDIM + t];
        v /= (float)n;
    }
    float ss = v * v;
    #pragma unroll
    for (int o = 32; o > 0; o >>= 1) ss += __shfl_xor(ss, o);
    __shared__ float sh[4];
    if ((t & 63) == 0) sh[t >> 6] = ss;
    __syncthreads();
    float tot = sh[0] + sh[1] + sh[2] + sh[3];
    float r = 1.0f / fmaxf(sqrtf(tot), 1e-12f);
    Bm[(size_t)c * FDIM + t] = __float2bfloat16(v * r);
}

// Fused GEMM: sims tile [128x128], epilogue: exp, neg-sum accumulation, positive capture.
#define BM 128
#define BN 128
#define BK 32
#define NKSTEP (FDIM / BK)

__global__ __launch_bounds__(256, 2)
void gemm_kernel(const __hip_bfloat16* __restrict__ A, const __hip_bfloat16* __restrict__ Bm,
                 const float* __restrict__ pm, float* __restrict__ negsum,
                 int* __restrict__ poscount, float2* __restrict__ posbuf) {
    __shared__ alignas(16) __hip_bfloat16 As[2][BM * BK];
    __shared__ alignas(16) __hip_bfloat16 Bs[2][BM * BK];
    __shared__ float rowsum[BM];

    const int t = threadIdx.x;
    const int bn0 = blockIdx.x * BN;
    const int bm0 = blockIdx.y * BM;
    if (t < BM) rowsum[t] = 0.f;

    const int lane = t & 63;
    const int wave = t >> 6;
    const int wr = wave >> 1, wc = wave & 1;
    const int lrow = lane & 15, lq = lane >> 4;

    const int sr = t >> 2;            // staging row 0..63
    const int sk = (t & 3) * 8;       // staging k chunk

    f32x4 acc[4][4];
    #pragma unroll
    for (int m = 0; m < 4; ++m)
        #pragma unroll
        for (int n = 0; n < 4; ++n) acc[m][n] = (f32x4)0.f;

    // stage k-step 0 into buffer 0
    {
        const __hip_bfloat16* ag = A + (size_t)(bm0 + sr) * FDIM + sk;
        const __hip_bfloat16* bg = Bm + (size_t)(bn0 + sr) * FDIM + sk;
        gload_lds16(ag,             (void*)&As[0][t * 8]);
        gload_lds16(ag + 64 * FDIM, (void*)&As[0][2048 + t * 8]);
        gload_lds16(bg,             (void*)&Bs[0][t * 8]);
        gload_lds16(bg + 64 * FDIM, (void*)&Bs[0][2048 + t * 8]);
    }

    for (int ks = 0; ks < NKSTEP; ++ks) {
        __syncthreads();   // stage ks complete (vmcnt drained before barrier), prev reads done
        int cur = ks & 1;
        if (ks + 1 < NKSTEP) {
            int nxt = cur ^ 1;
            int k0 = (ks + 1) * BK;
            const __hip_bfloat16* ag = A + (size_t)(bm0 + sr) * FDIM + k0 + sk;
            const __hip_bfloat16* bg = Bm + (size_t)(bn0 + sr) * FDIM + k0 + sk;
            gload_lds16(ag,             (void*)&As[nxt][t * 8]);
            gload_lds16(ag + 64 * FDIM, (void*)&As[nxt][2048 + t * 8]);
            gload_lds16(bg,             (void*)&Bs[nxt][t * 8]);
            gload_lds16(bg + 64 * FDIM, (void*)&Bs[nxt][2048 + t * 8]);
        }
        short8 af[4], bf[4];
        #pragma unroll
        for (int m = 0; m < 4; ++m)
            af[m] = *(const short8*)&As[cur][(wr * 64 + m * 16 + lrow) * BK + lq * 8];
        #pragma unroll
        for (int n = 0; n < 4; ++n)
            bf[n] = *(const short8*)&Bs[cur][(wc * 64 + n * 16 + lrow) * BK + lq * 8];
        #pragma unroll
        for (int m = 0; m < 4; ++m)
            #pragma unroll
            for (int n = 0; n < 4; ++n)
                acc[m][n] = __builtin_amdgcn_mfma_f32_16x16x32_bf16(af[m], bf[n], acc[m][n], 0, 0, 0);
    }

    // epilogue: C/D layout col = lane&15, row = (lane>>4)*4 + reg
    #pragma unroll
    for (int m = 0; m < 4; ++m) {
        #pragma unroll
        for (int r = 0; r < 4; ++r) {
            int rl = wr * 64 + m * 16 + lq * 4 + r;
            int grow = bm0 + rl;
            float pneg = 0.f;
            #pragma unroll
            for (int n = 0; n < 4; ++n) {
                int gcol = bn0 + wc * 64 + n * 16 + lrow;
                float s = acc[m][n][r];
                if (gcol < NCLOTHES) {
                    float pmv = pm[(size_t)grow * NCLOTHES + gcol];
                    float e = __expf(s);
                    if (pmv < 0.5f) {
                        pneg += e;
                    } else {
                        int slot = atomicAdd(&poscount[grow], 1);
                        if (slot < MAXPOS)
                            posbuf[(size_t)grow * MAXPOS + slot] = make_float2(s, __int_as_float(gcol));
                    }
                }
            }
            #pragma unroll
            for (int o = 1; o < 16; o <<= 1) pneg += __shfl_xor(pneg, o);
            if (lrow == 0) atomicAdd(&rowsum[rl], pneg);
        }
    }
    __syncthreads();
    if (t < BM) {
        float v = rowsum[t];
        if (v != 0.f) atomicAdd(&negsum[bm0 + t], v);
    }
}

__global__ void finish_kernel(const float* __restrict__ negsum, const int* __restrict__ poscount,
                              const float2* __restrict__ posbuf, const int* __restrict__ tg,
                              float* __restrict__ loss_rows) {
    int b = blockIdx.x, t = threadIdx.x;
    float ns = negsum[b];
    int n = poscount[b];
    if (n > MAXPOS) n = MAXPOS;
    int tgt = tg[b];
    float slp = 0.f, idlp = 0.f;
    for (int i = t; i < n; i += 256) {
        float2 v = posbuf[(size_t)b * MAXPOS + i];
        float s = v.x;
        int c = __float_as_int(v.y);
        float lp = s - __logf(ns + __expf(s));
        slp += lp;
        if (c == tgt) idlp = lp;
    }
    #pragma unroll
    for (int o = 32; o > 0; o >>= 1) { slp += __shfl_xor(slp, o); idlp += __shfl_xor(idlp, o); }
    __shared__ float sh1[4], sh2[4];
    if ((t & 63) == 0) { sh1[t >> 6] = slp; sh2[t >> 6] = idlp; }
    __syncthreads();
    if (t == 0) {
        float s_all = sh1[0] + sh1[1] + sh1[2] + sh1[3];
        float i_all = sh2[0] + sh2[1] + sh2[2] + sh2[3];
        loss_rows[b] = -((1.0f - EPSW) * i_all + (EPSW / (float)n) * s_all);
    }
}

__global__ void reduce_kernel(const float* __restrict__ lr, float* __restrict__ out) {
    int t = threadIdx.x;
    float s = lr[t] + lr[t + 256] + lr[t + 512] + lr[t + 768];
    #pragma unroll
    for (int o = 32; o > 0; o >>= 1) s += __shfl_xor(s, o);
    __shared__ float sh[4];
    if ((t & 63) == 0) sh[t >> 6] = s;
    __syncthreads();
    if (t == 0) out[0] = (sh[0] + sh[1] + sh[2] + sh[3]) * (1.0f / NBATCH);
}

extern "C" void kernel_launch(void* const* d_in, const int* in_sizes, int n_in,
                              void* d_out, int out_size, void* d_ws, size_t ws_size,
                              hipStream_t stream) {
    const float* inputs  = (const float*)d_in[0];
    const float* fm      = (const float*)d_in[1];
    const float* pmask   = (const float*)d_in[2];
    const int*   targets = (const int*)d_in[3];
    float* out = (float*)d_out;

    char* ws = (char*)d_ws;
    size_t off = 0;
    __hip_bfloat16* A = (__hip_bfloat16*)(ws + off);  off += (size_t)NBATCH * FDIM * 2;       // 512 KB
    __hip_bfloat16* Bm = (__hip_bfloat16*)(ws + off); off += (size_t)CPAD * FDIM * 2;         // 25.6 MB
    off = (off + 255) & ~(size_t)255;
    float* negsum = (float*)(ws + off);    off += 4096;
    int* poscount = (int*)(ws + off);      off += 4096;
    float* loss_rows = (float*)(ws + off); off += 4096;
    float2* posbuf = (float2*)(ws + off);  off += (size_t)NBATCH * MAXPOS * sizeof(float2);   // 8 MB

    zero_kernel<<<8, 256, 0, stream>>>(negsum, poscount);
    anorm_kernel<<<NBATCH, 256, 0, stream>>>(inputs, A);
    bnorm_kernel<<<CPAD, 256, 0, stream>>>(fm, inputs, targets, Bm);
    gemm_kernel<<<dim3(CPAD / BN, NBATCH / BM), 256, 0, stream>>>(A, Bm, pmask, negsum, poscount, posbuf);
    finish_kernel<<<NBATCH, 256, 0, stream>>>(negsum, poscount, posbuf, targets, loss_rows);
    reduce_kernel<<<1, 256, 0, stream>>>(loss_rows, out);
}